// Round 4
// baseline (355.332 us; speedup 1.0000x reference)
//
#include <hip/hip_runtime.h>
#include <hip/hip_bf16.h>
#include <cstdint>
#include <cstddef>

#define NB 2
#define NPT 20000
#define KNN 17
#define CH 128
#define NT32 (NPT/32)
#define NTB 313            // ceil(20000/64) blocks of 64 points
#define EPSV 1e-5f

typedef short short8 __attribute__((ext_vector_type(8)));
typedef float f32x4 __attribute__((ext_vector_type(4)));
typedef float f32x2 __attribute__((ext_vector_type(2)));
typedef unsigned short u16;

__device__ __forceinline__ u16 f2bf(float x) {
    union { float f; unsigned int u; } v; v.f = x;
    unsigned int r = v.u + 0x7FFFu + ((v.u >> 16) & 1u);   // RNE
    return (u16)(r >> 16);
}
__device__ __forceinline__ unsigned pack_bf2(float a, float b) {
    __hip_bfloat162 h2 = __float22bfloat162_rn(make_float2(a, b));
    union { __hip_bfloat162 h; unsigned u; } cv; cv.h = h2; return cv.u;
}
__device__ __forceinline__ f32x2 bfpair(unsigned w) {
    union { unsigned u; float f; } lo, hi;
    lo.u = w << 16; hi.u = w & 0xffff0000u;
    f32x2 r; r[0] = lo.f; r[1] = hi.f; return r;
}
__device__ __forceinline__ short8 packrow(const float* wrow) {
    float4 w0 = *(const float4*)(wrow);
    float4 w1 = *(const float4*)(wrow + 4);
    uint4 uu;
    uu.x = pack_bf2(w0.x, w0.y); uu.y = pack_bf2(w0.z, w0.w);
    uu.z = pack_bf2(w1.x, w1.y); uu.w = pack_bf2(w1.z, w1.w);
    union { uint4 u; short8 s; } cv; cv.u = uu; return cv.s;
}

// ---------------- Kernel 1: F[b][n][g] = relu(bn(Wf @ feats[:,n])), bf16 ----
__global__ __launch_bounds__(256) void k_feats(
    const float* __restrict__ feats, const float* __restrict__ Wf,
    const float* __restrict__ bfv, const float* __restrict__ gf,
    const float* __restrict__ betaf, const float* __restrict__ mf,
    const float* __restrict__ vf, u16* __restrict__ Fout)
{
    __shared__ u16 A_lds[32][136];   // [pt][ch]
    __shared__ u16 O_lds[32][136];   // [pt][g]
    const int t  = threadIdx.x;
    const int b  = blockIdx.x / NT32;
    const int n0 = (blockIdx.x % NT32) * 32;

    {
        const int chunk = t & 7;
        const int cbase = t >> 3;
        const float* base = feats + (size_t)b*CH*NPT + n0 + chunk*4;
        #pragma unroll
        for (int it = 0; it < 4; ++it) {
            int c = it*32 + cbase;
            float4 v = *(const float4*)(base + (size_t)c*NPT);
            A_lds[chunk*4+0][c] = f2bf(v.x);
            A_lds[chunk*4+1][c] = f2bf(v.y);
            A_lds[chunk*4+2][c] = f2bf(v.z);
            A_lds[chunk*4+3][c] = f2bf(v.w);
        }
    }

    const int lane = t & 63, wid = t >> 6;
    const int h = lane >> 4, r16 = lane & 15;
    const int gb = wid * 32;

    short8 bfrag[2][4];
    float sf[2], tf[2];
    #pragma unroll
    for (int T = 0; T < 2; ++T) {
        int g = gb + T*16 + r16;
        #pragma unroll
        for (int s = 0; s < 4; ++s)
            bfrag[T][s] = packrow(Wf + g*CH + s*32 + h*8);
        float inv = gf[g] * rsqrtf(vf[g] + EPSV);
        sf[T] = inv;
        tf[T] = bfv[g]*inv + betaf[g] - mf[g]*inv;
    }
    __syncthreads();

    #pragma unroll
    for (int sub = 0; sub < 2; ++sub) {
        short8 a[4];
        #pragma unroll
        for (int s = 0; s < 4; ++s)
            a[s] = *(const short8*)&A_lds[sub*16 + r16][s*32 + h*8];
        #pragma unroll
        for (int T = 0; T < 2; ++T) {
            f32x4 acc = {0.f, 0.f, 0.f, 0.f};
            #pragma unroll
            for (int s = 0; s < 4; ++s)
                acc = __builtin_amdgcn_mfma_f32_16x16x32_bf16(a[s], bfrag[T][s], acc, 0, 0, 0);
            #pragma unroll
            for (int r = 0; r < 4; ++r) {
                float y = fmaxf(fmaf(sf[T], acc[r], tf[T]), 0.f);
                O_lds[sub*16 + 4*h + r][gb + T*16 + r16] = f2bf(y);
            }
        }
    }
    __syncthreads();

    {
        const int pp = t >> 3, cc = (t & 7) * 16;
        uint4 v0 = *(const uint4*)&O_lds[pp][cc];
        uint4 v1 = *(const uint4*)&O_lds[pp][cc + 8];
        u16* dst = Fout + ((size_t)b*NPT + n0 + pp)*CH + cc;
        *(uint4*)dst = v0;
        *(uint4*)(dst + 8) = v1;
    }
}

// ---------------- Kernel 2: wave-independent fused gather+product+GEMM -----
struct PrefV { uint4 f[4]; };

__global__ __launch_bounds__(256, 2) void k_main(
    const float* __restrict__ pts, const int* __restrict__ knn,
    const u16* __restrict__ F,
    const float* __restrict__ Wd, const float* __restrict__ bd,
    const float* __restrict__ gd, const float* __restrict__ betad,
    const float* __restrict__ md, const float* __restrict__ vd,
    const float* __restrict__ Wp, const float* __restrict__ bp,
    const float* __restrict__ gp, const float* __restrict__ betap,
    const float* __restrict__ mp, const float* __restrict__ vp,
    float* __restrict__ out)
{
    __shared__ u16    Ab[4*2*16*128];     // per-wave double-buffered A, swizzled
    __shared__ int    idxl[4][16][KNN];
    __shared__ float2 d2l [4][16][KNN];
    __shared__ float  dzl [4][16][KNN];
    __shared__ float4 dcoef[CH];

    const int t    = threadIdx.x;
    const int b    = blockIdx.x / NTB;
    const int n0   = (blockIdx.x % NTB) * 64;
    const int lane = t & 63, w = t >> 6;
    const int h    = lane >> 4, j = lane & 15;
    const int n0w  = n0 + w*16;
    const bool valid = n0w < NPT;          // 16 | NPT so waves are all-or-nothing

    const float* px = pts + (size_t)b*3*NPT;
    const float* py = px + NPT;
    const float* pz = py + NPT;

    if (t < CH) {
        float inv = gd[t] * rsqrtf(vd[t] + EPSV);
        float td  = bd[t]*inv + betad[t] - md[t]*inv;
        dcoef[t]  = make_float4(Wd[t*3]*inv, Wd[t*3+1]*inv, Wd[t*3+2]*inv, td);
    }

    if (valid) {
        // per-wave idx + center-folded delta precompute (wave-local LDS)
        const int* krow = knn + ((size_t)b*NPT + n0w)*KNN;
        int*    idst = &idxl[w][0][0];
        float2* d2st = &d2l[w][0][0];
        float*  dzst = &dzl[w][0][0];
        #pragma unroll 1
        for (int tau = lane; tau < 16*KNN; tau += 64) {
            int r  = tau / KNN;
            int nb = krow[tau];
            idst[tau] = nb;
            d2st[tau] = make_float2(px[nb] - px[n0w+r], py[nb] - py[n0w+r]);
            dzst[tau] = pz[nb] - pz[n0w+r];
        }
    }
    __syncthreads();      // only for dcoef (cross-wave); sole barrier
    if (!valid) return;

    // B fragments for ALL 8 column tiles of Wp + folded BN coeffs
    short8 bfrag[8][4];
    float spv[8], tpv[8];
    #pragma unroll
    for (int T = 0; T < 8; ++T) {
        int g = T*16 + j;
        #pragma unroll
        for (int s = 0; s < 4; ++s)
            bfrag[T][s] = packrow(Wp + g*CH + s*32 + h*8);
        float inv = gp[g] * rsqrtf(vp[g] + EPSV);
        spv[T] = inv;
        tpv[T] = bp[g]*inv + betap[g] - mp[g]*inv;
    }

    // d-branch coefficients for this lane's channels j*8..j*8+7
    const int c0 = j*8;
    f32x2 wx2[4], wy2[4], wz2[4], t2[4];
    #pragma unroll
    for (int q = 0; q < 4; ++q) {
        float4 a = dcoef[c0 + 2*q];
        float4 c = dcoef[c0 + 2*q + 1];
        wx2[q][0]=a.x; wx2[q][1]=c.x;
        wy2[q][0]=a.y; wy2[q][1]=c.y;
        wz2[q][0]=a.z; wz2[q][1]=c.z;
        t2[q][0]=a.w;  t2[q][1]=c.w;
    }

    u16* buf0 = Ab + w*4096;
    u16* buf1 = buf0 + 2048;
    const u16* Fbj = F + (size_t)b*NPT*CH + c0;

    f32x4 facc[8] = {};

    auto loadPlane = [&](int k) {
        PrefV P;
        #pragma unroll
        for (int m = 0; m < 4; ++m) {
            int nb = idxl[w][h + 4*m][k];
            P.f[m] = *(const uint4*)(Fbj + (size_t)nb*CH);
        }
        return P;
    };
    auto stage = [&](u16* bufp, const PrefV& P, int k) {
        #pragma unroll
        for (int m = 0; m < 4; ++m) {
            const int r = h + 4*m;
            float2 dd = d2l[w][r][k];
            float  dz = dzl[w][r][k];
            const unsigned fw[4] = {P.f[m].x, P.f[m].y, P.f[m].z, P.f[m].w};
            const f32x2 z2 = {0.f, 0.f};
            unsigned pk[4];
            #pragma unroll
            for (int q = 0; q < 4; ++q) {
                f32x2 d = wx2[q]*dd.x + wy2[q]*dd.y + wz2[q]*dz + t2[q];
                d = __builtin_elementwise_max(d, z2);
                f32x2 pr = d * bfpair(fw[q]);
                pk[q] = pack_bf2(pr[0], pr[1]);
            }
            uint4 v; v.x = pk[0]; v.y = pk[1]; v.z = pk[2]; v.w = pk[3];
            *(uint4*)(bufp + r*128 + ((j*8) ^ ((r&7)*8))) = v;   // XOR-swizzled
        }
    };
    auto mfmaP = [&](const u16* bufp) {
        short8 a[4];
        #pragma unroll
        for (int s = 0; s < 4; ++s)
            a[s] = *(const short8*)(bufp + j*128 + ((s*32 + h*8) ^ ((j&7)*8)));
        const f32x4 z4 = {0.f,0.f,0.f,0.f};
        #pragma unroll
        for (int T = 0; T < 8; ++T) {
            f32x4 acc = z4;
            #pragma unroll
            for (int s = 0; s < 4; ++s)
                acc = __builtin_amdgcn_mfma_f32_16x16x32_bf16(a[s], bfrag[T][s], acc, 0, 0, 0);
            f32x4 y = acc * spv[T] + tpv[T];
            y = __builtin_elementwise_max(y, z4);
            facc[T] += y;
        }
    };

    // barrier-free software-pipelined k-loop (dbuf parity: plane k in buf[k&1])
    PrefV PA = loadPlane(0);
    stage(buf0, PA, 0);
    PA = loadPlane(1);
    PrefV PB = loadPlane(2);
    #pragma unroll 1
    for (int i = 0; i < 8; ++i) {
        const int k = 2*i;
        stage(buf1, PA, k+1);
        if (k + 3 <= 16) PA = loadPlane(k+3);
        mfmaP(buf0);                            // plane k
        stage(buf0, PB, k+2);
        if (k + 4 <= 16) PB = loadPlane(k+4);
        mfmaP(buf1);                            // plane k+1
    }
    mfmaP(buf0);                                // plane 16

    #pragma unroll
    for (int T = 0; T < 8; ++T) {
        int g = T*16 + j;
        *(f32x4*)(out + ((size_t)b*CH + g)*NPT + n0w + 4*h) = facc[T];
    }
}

extern "C" void kernel_launch(void* const* d_in, const int* in_sizes, int n_in,
                              void* d_out, int out_size, void* d_ws, size_t ws_size,
                              hipStream_t stream)
{
    const float* feats = (const float*)d_in[0];
    const float* pts   = (const float*)d_in[1];
    const int*   knn   = (const int*)d_in[2];
    const float* Wd    = (const float*)d_in[3];
    const float* bd    = (const float*)d_in[4];
    const float* gd    = (const float*)d_in[5];
    const float* betad = (const float*)d_in[6];
    const float* md    = (const float*)d_in[7];
    const float* vd    = (const float*)d_in[8];
    const float* Wf    = (const float*)d_in[9];
    const float* bfv   = (const float*)d_in[10];
    const float* gf    = (const float*)d_in[11];
    const float* betaf = (const float*)d_in[12];
    const float* mf    = (const float*)d_in[13];
    const float* vf    = (const float*)d_in[14];
    const float* Wp    = (const float*)d_in[15];
    const float* bp    = (const float*)d_in[16];
    const float* gp    = (const float*)d_in[17];
    const float* betap = (const float*)d_in[18];
    const float* mp    = (const float*)d_in[19];
    const float* vp    = (const float*)d_in[20];
    float* out = (float*)d_out;
    u16* Fws = (u16*)d_ws;   // B*N*128 bf16 = 10.24 MB

    k_feats<<<dim3(NB * NT32), 256, 0, stream>>>(feats, Wf, bfv, gf, betaf, mf, vf, Fws);
    k_main <<<dim3(NB * NTB), 256, 0, stream>>>(pts, knn, Fws, Wd, bd, gd, betad, md, vd,
                                                Wp, bp, gp, betap, mp, vp, out);
}

// Round 5
// 143.379 us; speedup vs baseline: 2.4783x; 2.4783x over previous
//
#include <hip/hip_runtime.h>
#include <hip/hip_bf16.h>
#include <cstdint>
#include <cstddef>

#define NB 2
#define NPT 20000
#define KNN 17
#define CH 128
#define NT32 (NPT/32)
#define NTB 313            // ceil(20000/64) blocks of 64 points
#define EPSV 1e-5f

typedef short short8 __attribute__((ext_vector_type(8)));
typedef float f32x4 __attribute__((ext_vector_type(4)));
typedef float f32x2 __attribute__((ext_vector_type(2)));
typedef unsigned short u16;

__device__ __forceinline__ u16 f2bf(float x) {
    union { float f; unsigned int u; } v; v.f = x;
    unsigned int r = v.u + 0x7FFFu + ((v.u >> 16) & 1u);   // RNE
    return (u16)(r >> 16);
}
__device__ __forceinline__ unsigned pack_bf2(float a, float b) {
    __hip_bfloat162 h2 = __float22bfloat162_rn(make_float2(a, b));
    union { __hip_bfloat162 h; unsigned u; } cv; cv.h = h2; return cv.u;
}
__device__ __forceinline__ f32x2 bfpair(unsigned w) {
    union { unsigned u; float f; } lo, hi;
    lo.u = w << 16; hi.u = w & 0xffff0000u;
    f32x2 r; r[0] = lo.f; r[1] = hi.f; return r;
}
__device__ __forceinline__ short8 packrow(const float* wrow) {
    float4 w0 = *(const float4*)(wrow);
    float4 w1 = *(const float4*)(wrow + 4);
    uint4 uu;
    uu.x = pack_bf2(w0.x, w0.y); uu.y = pack_bf2(w0.z, w0.w);
    uu.z = pack_bf2(w1.x, w1.y); uu.w = pack_bf2(w1.z, w1.w);
    union { uint4 u; short8 s; } cv; cv.u = uu; return cv.s;
}

// ---------------- Kernel 1: F[b][n][g] = relu(bn(Wf @ feats[:,n])), bf16 ----
__global__ __launch_bounds__(256) void k_feats(
    const float* __restrict__ feats, const float* __restrict__ Wf,
    const float* __restrict__ bfv, const float* __restrict__ gf,
    const float* __restrict__ betaf, const float* __restrict__ mf,
    const float* __restrict__ vf, u16* __restrict__ Fout)
{
    __shared__ u16 A_lds[32][136];   // [pt][ch]
    __shared__ u16 O_lds[32][136];   // [pt][g]
    const int t  = threadIdx.x;
    const int b  = blockIdx.x / NT32;
    const int n0 = (blockIdx.x % NT32) * 32;

    {
        const int chunk = t & 7;
        const int cbase = t >> 3;
        const float* base = feats + (size_t)b*CH*NPT + n0 + chunk*4;
        #pragma unroll
        for (int it = 0; it < 4; ++it) {
            int c = it*32 + cbase;
            float4 v = *(const float4*)(base + (size_t)c*NPT);
            A_lds[chunk*4+0][c] = f2bf(v.x);
            A_lds[chunk*4+1][c] = f2bf(v.y);
            A_lds[chunk*4+2][c] = f2bf(v.z);
            A_lds[chunk*4+3][c] = f2bf(v.w);
        }
    }

    const int lane = t & 63, wid = t >> 6;
    const int h = lane >> 4, r16 = lane & 15;
    const int gb = wid * 32;

    short8 bfrag[2][4];
    float sf[2], tf[2];
    #pragma unroll
    for (int T = 0; T < 2; ++T) {
        int g = gb + T*16 + r16;
        #pragma unroll
        for (int s = 0; s < 4; ++s)
            bfrag[T][s] = packrow(Wf + g*CH + s*32 + h*8);
        float inv = gf[g] * rsqrtf(vf[g] + EPSV);
        sf[T] = inv;
        tf[T] = bfv[g]*inv + betaf[g] - mf[g]*inv;
    }
    __syncthreads();

    #pragma unroll
    for (int sub = 0; sub < 2; ++sub) {
        short8 a[4];
        #pragma unroll
        for (int s = 0; s < 4; ++s)
            a[s] = *(const short8*)&A_lds[sub*16 + r16][s*32 + h*8];
        #pragma unroll
        for (int T = 0; T < 2; ++T) {
            f32x4 acc = {0.f, 0.f, 0.f, 0.f};
            #pragma unroll
            for (int s = 0; s < 4; ++s)
                acc = __builtin_amdgcn_mfma_f32_16x16x32_bf16(a[s], bfrag[T][s], acc, 0, 0, 0);
            #pragma unroll
            for (int r = 0; r < 4; ++r) {
                float y = fmaxf(fmaf(sf[T], acc[r], tf[T]), 0.f);
                O_lds[sub*16 + 4*h + r][gb + T*16 + r16] = f2bf(y);
            }
        }
    }
    __syncthreads();

    {
        const int pp = t >> 3, cc = (t & 7) * 16;
        uint4 v0 = *(const uint4*)&O_lds[pp][cc];
        uint4 v1 = *(const uint4*)&O_lds[pp][cc + 8];
        u16* dst = Fout + ((size_t)b*NPT + n0 + pp)*CH + cc;
        *(uint4*)dst = v0;
        *(uint4*)(dst + 8) = v1;
    }
}

// ---------------- Kernel 2: wave-independent fused gather+product+GEMM -----
struct PrefV { uint4 f[4]; };

__global__ __launch_bounds__(256, 1) void k_main(
    const float* __restrict__ pts, const int* __restrict__ knn,
    const u16* __restrict__ F,
    const float* __restrict__ Wd, const float* __restrict__ bd,
    const float* __restrict__ gd, const float* __restrict__ betad,
    const float* __restrict__ md, const float* __restrict__ vd,
    const float* __restrict__ Wp, const float* __restrict__ bp,
    const float* __restrict__ gp, const float* __restrict__ betap,
    const float* __restrict__ mp, const float* __restrict__ vp,
    float* __restrict__ out)
{
    __shared__ u16    Ab[4*2*16*128];     // per-wave double-buffered A, swizzled
    __shared__ int    idxl[4][16][KNN];
    __shared__ float2 d2l [4][16][KNN];
    __shared__ float  dzl [4][16][KNN];

    const int t    = threadIdx.x;
    const int b    = blockIdx.x / NTB;
    const int n0   = (blockIdx.x % NTB) * 64;
    const int lane = t & 63, w = t >> 6;
    const int h    = lane >> 4, j = lane & 15;
    const int n0w  = n0 + w*16;
    if (n0w >= NPT) return;               // 16 | NPT -> whole-wave uniform

    const float* px = pts + (size_t)b*3*NPT;
    const float* py = px + NPT;
    const float* pz = py + NPT;

    // per-wave idx + center-folded delta precompute (wave-local LDS, no barrier)
    {
        const int* krow = knn + ((size_t)b*NPT + n0w)*KNN;
        int*    idst = &idxl[w][0][0];
        float2* d2st = &d2l[w][0][0];
        float*  dzst = &dzl[w][0][0];
        #pragma unroll 1
        for (int tau = lane; tau < 16*KNN; tau += 64) {
            int r  = tau / KNN;
            int nb = krow[tau];
            idst[tau] = nb;
            d2st[tau] = make_float2(px[nb] - px[n0w+r], py[nb] - py[n0w+r]);
            dzst[tau] = pz[nb] - pz[n0w+r];
        }
    }

    // B fragments for ALL 8 column tiles of Wp + folded BN coeffs
    short8 bfrag[8][4];
    float spv[8], tpv[8];
    #pragma unroll
    for (int T = 0; T < 8; ++T) {
        int g = T*16 + j;
        #pragma unroll
        for (int s = 0; s < 4; ++s)
            bfrag[T][s] = packrow(Wp + g*CH + s*32 + h*8);
        float inv = gp[g] * rsqrtf(vp[g] + EPSV);
        spv[T] = inv;
        tpv[T] = bp[g]*inv + betap[g] - mp[g]*inv;
    }

    // d-branch coefficients for this lane's channels c0..c0+7, straight from global
    const int c0 = j*8;
    f32x2 wx2[4], wy2[4], wz2[4], t2[4];
    #pragma unroll
    for (int q = 0; q < 4; ++q) {
        const int ca = c0 + 2*q, cb = ca + 1;
        float inva = gd[ca] * rsqrtf(vd[ca] + EPSV);
        float invb = gd[cb] * rsqrtf(vd[cb] + EPSV);
        wx2[q][0] = Wd[ca*3+0]*inva; wx2[q][1] = Wd[cb*3+0]*invb;
        wy2[q][0] = Wd[ca*3+1]*inva; wy2[q][1] = Wd[cb*3+1]*invb;
        wz2[q][0] = Wd[ca*3+2]*inva; wz2[q][1] = Wd[cb*3+2]*invb;
        t2[q][0]  = bd[ca]*inva + betad[ca] - md[ca]*inva;
        t2[q][1]  = bd[cb]*invb + betad[cb] - md[cb]*invb;
    }

    u16* buf0 = Ab + w*4096;
    u16* buf1 = buf0 + 2048;
    const u16* Fbj = F + (size_t)b*NPT*CH + c0;

    f32x4 facc[8] = {};

    auto loadPlane = [&](int k) {
        PrefV P;
        #pragma unroll
        for (int m = 0; m < 4; ++m) {
            int nb = idxl[w][h + 4*m][k];
            P.f[m] = *(const uint4*)(Fbj + (size_t)nb*CH);
        }
        return P;
    };
    auto stage = [&](u16* bufp, const PrefV& P, int k) {
        #pragma unroll
        for (int m = 0; m < 4; ++m) {
            const int r = h + 4*m;
            float2 dd = d2l[w][r][k];
            float  dz = dzl[w][r][k];
            const unsigned fw[4] = {P.f[m].x, P.f[m].y, P.f[m].z, P.f[m].w};
            const f32x2 z2 = {0.f, 0.f};
            unsigned pk[4];
            #pragma unroll
            for (int q = 0; q < 4; ++q) {
                f32x2 d = wx2[q]*dd.x + wy2[q]*dd.y + wz2[q]*dz + t2[q];
                d = __builtin_elementwise_max(d, z2);
                f32x2 pr = d * bfpair(fw[q]);
                pk[q] = pack_bf2(pr[0], pr[1]);
            }
            uint4 v; v.x = pk[0]; v.y = pk[1]; v.z = pk[2]; v.w = pk[3];
            *(uint4*)(bufp + r*128 + ((j*8) ^ ((r&7)*8)));   // address only (see below)
            *(uint4*)(bufp + r*128 + ((j*8) ^ ((r&7)*8))) = v;   // XOR-swizzled
        }
    };
    auto mfmaP = [&](const u16* bufp) {
        short8 a[4];
        #pragma unroll
        for (int s = 0; s < 4; ++s)
            a[s] = *(const short8*)(bufp + j*128 + ((s*32 + h*8) ^ ((j&7)*8)));
        const f32x4 z4 = {0.f,0.f,0.f,0.f};
        #pragma unroll
        for (int T = 0; T < 8; ++T) {
            f32x4 acc = z4;
            #pragma unroll
            for (int s = 0; s < 4; ++s)
                acc = __builtin_amdgcn_mfma_f32_16x16x32_bf16(a[s], bfrag[T][s], acc, 0, 0, 0);
            f32x4 y = acc * spv[T] + tpv[T];
            y = __builtin_elementwise_max(y, z4);
            facc[T] += y;
        }
    };

    // barrier-free software-pipelined k-loop (dbuf parity: plane k in buf[k&1])
    PrefV PA = loadPlane(0);
    stage(buf0, PA, 0);
    PA = loadPlane(1);
    PrefV PB = loadPlane(2);
    #pragma unroll 1
    for (int i = 0; i < 8; ++i) {
        const int k = 2*i;
        stage(buf1, PA, k+1);
        if (k + 3 <= 16) PA = loadPlane(k+3);
        mfmaP(buf0);                            // plane k
        stage(buf0, PB, k+2);
        if (k + 4 <= 16) PB = loadPlane(k+4);
        mfmaP(buf1);                            // plane k+1
    }
    mfmaP(buf0);                                // plane 16

    #pragma unroll
    for (int T = 0; T < 8; ++T) {
        int g = T*16 + j;
        *(f32x4*)(out + ((size_t)b*CH + g)*NPT + n0w + 4*h) = facc[T];
    }
}

extern "C" void kernel_launch(void* const* d_in, const int* in_sizes, int n_in,
                              void* d_out, int out_size, void* d_ws, size_t ws_size,
                              hipStream_t stream)
{
    const float* feats = (const float*)d_in[0];
    const float* pts   = (const float*)d_in[1];
    const int*   knn   = (const int*)d_in[2];
    const float* Wd    = (const float*)d_in[3];
    const float* bd    = (const float*)d_in[4];
    const float* gd    = (const float*)d_in[5];
    const float* betad = (const float*)d_in[6];
    const float* md    = (const float*)d_in[7];
    const float* vd    = (const float*)d_in[8];
    const float* Wf    = (const float*)d_in[9];
    const float* bfv   = (const float*)d_in[10];
    const float* gf    = (const float*)d_in[11];
    const float* betaf = (const float*)d_in[12];
    const float* mf    = (const float*)d_in[13];
    const float* vf    = (const float*)d_in[14];
    const float* Wp    = (const float*)d_in[15];
    const float* bp    = (const float*)d_in[16];
    const float* gp    = (const float*)d_in[17];
    const float* betap = (const float*)d_in[18];
    const float* mp    = (const float*)d_in[19];
    const float* vp    = (const float*)d_in[20];
    float* out = (float*)d_out;
    u16* Fws = (u16*)d_ws;   // B*N*128 bf16 = 10.24 MB

    k_feats<<<dim3(NB * NT32), 256, 0, stream>>>(feats, Wf, bfv, gf, betaf, mf, vf, Fws);
    k_main <<<dim3(NB * NTB), 256, 0, stream>>>(pts, knn, Fws, Wd, bd, gd, betad, md, vd,
                                                Wp, bp, gp, betap, mp, vp, out);
}

// Round 6
// 86.370 us; speedup vs baseline: 4.1140x; 1.6601x over previous
//
#include <hip/hip_runtime.h>
#include <hip/hip_bf16.h>
#include <cstdint>
#include <cstddef>

#define NB 2
#define NPT 20000
#define KNN 17
#define CH 128
#define NT16 (NPT/16)
#define NT32 (NPT/32)
#define EPSV 1e-5f

typedef short short8 __attribute__((ext_vector_type(8)));
typedef float f32x4 __attribute__((ext_vector_type(4)));
typedef float f32x2 __attribute__((ext_vector_type(2)));
typedef unsigned short u16;

__device__ __forceinline__ u16 f2bf(float x) {
    union { float f; unsigned int u; } v; v.f = x;
    unsigned int r = v.u + 0x7FFFu + ((v.u >> 16) & 1u);   // RNE
    return (u16)(r >> 16);
}
__device__ __forceinline__ unsigned pack_bf2(float a, float b) {
    __hip_bfloat162 h2 = __float22bfloat162_rn(make_float2(a, b));
    union { __hip_bfloat162 h; unsigned u; } cv; cv.h = h2; return cv.u;
}
__device__ __forceinline__ f32x2 bfpair(unsigned w) {
    union { unsigned u; float f; } lo, hi;
    lo.u = w << 16; hi.u = w & 0xffff0000u;
    f32x2 r; r[0] = lo.f; r[1] = hi.f; return r;
}
__device__ __forceinline__ short8 packrow_scaled(const float* wrow, float s) {
    float4 w0 = *(const float4*)(wrow);
    float4 w1 = *(const float4*)(wrow + 4);
    uint4 uu;
    uu.x = pack_bf2(w0.x*s, w0.y*s); uu.y = pack_bf2(w0.z*s, w0.w*s);
    uu.z = pack_bf2(w1.x*s, w1.y*s); uu.w = pack_bf2(w1.z*s, w1.w*s);
    union { uint4 u; short8 s8; } cv; cv.u = uu; return cv.s8;
}
__device__ __forceinline__ short8 packrow(const float* wrow) {
    return packrow_scaled(wrow, 1.0f);
}

// ---------------- Kernel 1: F[b][n][g] = relu(bn(Wf @ feats[:,n])), bf16 ----
__global__ __launch_bounds__(256) void k_feats(
    const float* __restrict__ feats, const float* __restrict__ Wf,
    const float* __restrict__ bfv, const float* __restrict__ gf,
    const float* __restrict__ betaf, const float* __restrict__ mf,
    const float* __restrict__ vf, u16* __restrict__ Fout)
{
    __shared__ u16 A_lds[32][136];   // [pt][ch]
    __shared__ u16 O_lds[32][136];   // [pt][g]
    const int t  = threadIdx.x;
    const int b  = blockIdx.x / NT32;
    const int n0 = (blockIdx.x % NT32) * 32;

    {
        const int chunk = t & 7;
        const int cbase = t >> 3;
        const float* base = feats + (size_t)b*CH*NPT + n0 + chunk*4;
        #pragma unroll
        for (int it = 0; it < 4; ++it) {
            int c = it*32 + cbase;
            float4 v = *(const float4*)(base + (size_t)c*NPT);
            A_lds[chunk*4+0][c] = f2bf(v.x);
            A_lds[chunk*4+1][c] = f2bf(v.y);
            A_lds[chunk*4+2][c] = f2bf(v.z);
            A_lds[chunk*4+3][c] = f2bf(v.w);
        }
    }

    const int lane = t & 63, wid = t >> 6;
    const int h = lane >> 4, r16 = lane & 15;
    const int gb = wid * 32;

    short8 bfrag[2][4];
    float sf[2], tf[2];
    #pragma unroll
    for (int T = 0; T < 2; ++T) {
        int g = gb + T*16 + r16;
        #pragma unroll
        for (int s = 0; s < 4; ++s)
            bfrag[T][s] = packrow(Wf + g*CH + s*32 + h*8);
        float inv = gf[g] * rsqrtf(vf[g] + EPSV);
        sf[T] = inv;
        tf[T] = bfv[g]*inv + betaf[g] - mf[g]*inv;
    }
    __syncthreads();

    #pragma unroll
    for (int sub = 0; sub < 2; ++sub) {
        short8 a[4];
        #pragma unroll
        for (int s = 0; s < 4; ++s)
            a[s] = *(const short8*)&A_lds[sub*16 + r16][s*32 + h*8];
        #pragma unroll
        for (int T = 0; T < 2; ++T) {
            f32x4 acc = {0.f, 0.f, 0.f, 0.f};
            #pragma unroll
            for (int s = 0; s < 4; ++s)
                acc = __builtin_amdgcn_mfma_f32_16x16x32_bf16(a[s], bfrag[T][s], acc, 0, 0, 0);
            #pragma unroll
            for (int r = 0; r < 4; ++r) {
                float y = fmaxf(fmaf(sf[T], acc[r], tf[T]), 0.f);
                O_lds[sub*16 + 4*h + r][gb + T*16 + r16] = f2bf(y);
            }
        }
    }
    __syncthreads();

    {
        const int pp = t >> 3, cc = (t & 7) * 16;
        uint4 v0 = *(const uint4*)&O_lds[pp][cc];
        uint4 v1 = *(const uint4*)&O_lds[pp][cc + 8];
        u16* dst = Fout + ((size_t)b*NPT + n0 + pp)*CH + cc;
        *(uint4*)dst = v0;
        *(uint4*)(dst + 8) = v1;
    }
}

// ---------------- Kernel 2: block-shared A-plane, lean LDS, 1 barrier/plane
struct Pref { float4 m; uint4 f; };

__global__ __launch_bounds__(256) void k_main(
    const float* __restrict__ pts, const int* __restrict__ knn,
    const u16* __restrict__ F,
    const float* __restrict__ Wd, const float* __restrict__ bd,
    const float* __restrict__ gd, const float* __restrict__ betad,
    const float* __restrict__ md, const float* __restrict__ vd,
    const float* __restrict__ Wp, const float* __restrict__ bp,
    const float* __restrict__ gp, const float* __restrict__ betap,
    const float* __restrict__ mp, const float* __restrict__ vp,
    float* __restrict__ out)
{
    __shared__ u16   Abuf[2][16*128];      // 8 KB, XOR-swizzled rows
    __shared__ float4 meta[16][KNN];       // [dx,dy,dz,bitcast(idx)] 4.35 KB

    const int t  = threadIdx.x;
    const int b  = blockIdx.x / NT16;
    const int n0 = (blockIdx.x % NT16) * 16;

    const float* px = pts + (size_t)b*3*NPT;
    const float* py = px + NPT;
    const float* pz = py + NPT;

    // meta: neighbor idx + center-folded deltas (once per block)
    {
        const int* krow = knn + ((size_t)b*NPT + n0)*KNN;
        #pragma unroll 1
        for (int tau = t; tau < 16*KNN; tau += 256) {
            int r  = tau / KNN;
            int nb = krow[tau];
            float4 m;
            m.x = px[nb] - px[n0+r];
            m.y = py[nb] - py[n0+r];
            m.z = pz[nb] - pz[n0+r];
            m.w = __int_as_float(nb);
            (&meta[0][0])[tau] = m;
        }
    }
    __syncthreads();                       // meta ready

    const int p_t = t >> 4, j_t = t & 15, c0 = j_t*8;   // staging role
    const int lane = t & 63, wid = t >> 6;
    const int h = lane >> 4, r16 = lane & 15;
    const int gb = wid * 32;
    const u16* Fbj = F + (size_t)b*NPT*CH + c0;

    // hoisted LDS offsets
    const int wOff = p_t*128 + (c0 ^ ((p_t&7)*8));        // stage write (u16 idx)
    int rOff[4];
    #pragma unroll
    for (int s = 0; s < 4; ++s)
        rOff[s] = r16*128 + ((s*32 + h*8) ^ ((r16&7)*8)); // mfma reads

    auto issueK = [&](int k)->Pref {
        Pref P;
        P.m = meta[p_t][k];
        int nb = __float_as_int(P.m.w);
        P.f = *(const uint4*)(Fbj + (size_t)nb*CH);
        return P;
    };

    // prefetch planes 0,1 right away (latency hides under prologue below)
    Pref PA = issueK(0);
    Pref PB = issueK(1);

    // B fragments: s-scale folded into bf16 weights; epilogue uses max(acc,-t)
    short8 bfrag[2][4];
    float tpv[2];
    #pragma unroll
    for (int T = 0; T < 2; ++T) {
        int g = gb + T*16 + r16;
        float inv = gp[g] * rsqrtf(vp[g] + EPSV);
        #pragma unroll
        for (int s = 0; s < 4; ++s)
            bfrag[T][s] = packrow_scaled(Wp + g*CH + s*32 + h*8, inv);
        tpv[T] = bp[g]*inv + betap[g] - mp[g]*inv;
    }

    // d-branch coefficients for channels c0..c0+7, straight from global (L2-hot)
    f32x2 wx2[4], wy2[4], wz2[4], t2[4];
    #pragma unroll
    for (int q = 0; q < 4; ++q) {
        const int ca = c0 + 2*q, cb = ca + 1;
        float inva = gd[ca] * rsqrtf(vd[ca] + EPSV);
        float invb = gd[cb] * rsqrtf(vd[cb] + EPSV);
        wx2[q][0] = Wd[ca*3+0]*inva; wx2[q][1] = Wd[cb*3+0]*invb;
        wy2[q][0] = Wd[ca*3+1]*inva; wy2[q][1] = Wd[cb*3+1]*invb;
        wz2[q][0] = Wd[ca*3+2]*inva; wz2[q][1] = Wd[cb*3+2]*invb;
        t2[q][0]  = bd[ca]*inva + betad[ca] - md[ca]*inva;
        t2[q][1]  = bd[cb]*invb + betad[cb] - md[cb]*invb;
    }

    auto stage = [&](u16* A, const Pref& P) {
        const unsigned fw[4] = {P.f.x, P.f.y, P.f.z, P.f.w};
        const f32x2 z2 = {0.f, 0.f};
        unsigned pk[4];
        #pragma unroll
        for (int q = 0; q < 4; ++q) {
            f32x2 d = wx2[q]*P.m.x + wy2[q]*P.m.y + wz2[q]*P.m.z + t2[q];
            d = __builtin_elementwise_max(d, z2);
            f32x2 pr = d * bfpair(fw[q]);
            pk[q] = pack_bf2(pr[0], pr[1]);
        }
        uint4 v; v.x = pk[0]; v.y = pk[1]; v.z = pk[2]; v.w = pk[3];
        *(uint4*)(A + wOff) = v;
    };

    f32x4 facc[2] = {};
    auto mfmaP = [&](const u16* A) {
        short8 a[4];
        #pragma unroll
        for (int s = 0; s < 4; ++s)
            a[s] = *(const short8*)(A + rOff[s]);
        #pragma unroll
        for (int T = 0; T < 2; ++T) {
            f32x4 acc = {0.f,0.f,0.f,0.f};
            #pragma unroll
            for (int s = 0; s < 4; ++s)
                acc = __builtin_amdgcn_mfma_f32_16x16x32_bf16(a[s], bfrag[T][s], acc, 0, 0, 0);
            f32x4 nt = {-tpv[T], -tpv[T], -tpv[T], -tpv[T]};
            facc[T] += __builtin_elementwise_max(acc, nt);   // relu folded: +17t at end
        }
    };

    // prologue: stage plane 0 into buf0; refill pipeline
    stage(Abuf[0], PA);
    PA = PB;
    PB = issueK(2);
    __syncthreads();

    int p = 0;
    #pragma unroll 1
    for (int k = 0; k < 16; ++k) {
        stage(Abuf[p^1], PA);              // plane k+1
        PA = PB;
        if (k + 3 <= 16) PB = issueK(k+3);
        mfmaP(Abuf[p]);                    // plane k
        __syncthreads();
        p ^= 1;
    }
    mfmaP(Abuf[p]);                        // plane 16

    #pragma unroll
    for (int T = 0; T < 2; ++T) {
        int g = gb + T*16 + r16;
        f32x4 o = facc[T] + (float)KNN * tpv[T];
        *(f32x4*)(out + ((size_t)b*CH + g)*NPT + n0 + 4*h) = o;
    }
}

extern "C" void kernel_launch(void* const* d_in, const int* in_sizes, int n_in,
                              void* d_out, int out_size, void* d_ws, size_t ws_size,
                              hipStream_t stream)
{
    const float* feats = (const float*)d_in[0];
    const float* pts   = (const float*)d_in[1];
    const int*   knn   = (const int*)d_in[2];
    const float* Wd    = (const float*)d_in[3];
    const float* bd    = (const float*)d_in[4];
    const float* gd    = (const float*)d_in[5];
    const float* betad = (const float*)d_in[6];
    const float* md    = (const float*)d_in[7];
    const float* vd    = (const float*)d_in[8];
    const float* Wf    = (const float*)d_in[9];
    const float* bfv   = (const float*)d_in[10];
    const float* gf    = (const float*)d_in[11];
    const float* betaf = (const float*)d_in[12];
    const float* mf    = (const float*)d_in[13];
    const float* vf    = (const float*)d_in[14];
    const float* Wp    = (const float*)d_in[15];
    const float* bp    = (const float*)d_in[16];
    const float* gp    = (const float*)d_in[17];
    const float* betap = (const float*)d_in[18];
    const float* mp    = (const float*)d_in[19];
    const float* vp    = (const float*)d_in[20];
    float* out = (float*)d_out;
    u16* Fws = (u16*)d_ws;   // B*N*128 bf16 = 10.24 MB

    k_feats<<<dim3(NB * NT32), 256, 0, stream>>>(feats, Wf, bfv, gf, betaf, mf, vf, Fws);
    k_main <<<dim3(NB * NT16), 256, 0, stream>>>(pts, knn, Fws, Wd, bd, gd, betad, md, vd,
                                                 Wp, bp, gp, betap, mp, vp, out);
}

// Round 7
// 84.009 us; speedup vs baseline: 4.2297x; 1.0281x over previous
//
#include <hip/hip_runtime.h>
#include <hip/hip_bf16.h>
#include <cstdint>
#include <cstddef>

#define NB 2
#define NPT 20000
#define KNN 17
#define CH 128
#define NT16 (NPT/16)
#define NT32 (NPT/32)
#define EPSV 1e-5f

typedef short short8 __attribute__((ext_vector_type(8)));
typedef float f32x4 __attribute__((ext_vector_type(4)));
typedef float f32x2 __attribute__((ext_vector_type(2)));
typedef unsigned short u16;

// 1-op packed f32->bf16 (RNE), gfx950 HW instruction
__device__ __forceinline__ unsigned cvtpk(float lo, float hi) {
    unsigned r;
    asm("v_cvt_pk_bf16_f32 %0, %1, %2" : "=v"(r) : "v"(lo), "v"(hi));
    return r;
}
__device__ __forceinline__ u16 f2bf1(float x) {
    return (u16)cvtpk(x, x);
}
__device__ __forceinline__ f32x2 bfpair(unsigned w) {
    union { unsigned u; float f; } lo, hi;
    lo.u = w << 16; hi.u = w & 0xffff0000u;
    f32x2 r; r[0] = lo.f; r[1] = hi.f; return r;
}
__device__ __forceinline__ short8 packrow_scaled(const float* wrow, float s) {
    float4 w0 = *(const float4*)(wrow);
    float4 w1 = *(const float4*)(wrow + 4);
    uint4 uu;
    uu.x = cvtpk(w0.x*s, w0.y*s); uu.y = cvtpk(w0.z*s, w0.w*s);
    uu.z = cvtpk(w1.x*s, w1.y*s); uu.w = cvtpk(w1.z*s, w1.w*s);
    union { uint4 u; short8 s8; } cv; cv.u = uu; return cv.s8;
}
__device__ __forceinline__ short8 packrow(const float* wrow) {
    return packrow_scaled(wrow, 1.0f);
}
// barrier that drains LDS ops only — global prefetches stay in flight (T4-lite)
__device__ __forceinline__ void lds_barrier() {
    asm volatile("s_waitcnt lgkmcnt(0)\n\ts_barrier" ::: "memory");
}

// ---------------- Kernel 1: F[b][n][g] = relu(bn(Wf @ feats[:,n])), bf16 ----
__global__ __launch_bounds__(256) void k_feats(
    const float* __restrict__ feats, const float* __restrict__ Wf,
    const float* __restrict__ bfv, const float* __restrict__ gf,
    const float* __restrict__ betaf, const float* __restrict__ mf,
    const float* __restrict__ vf, u16* __restrict__ Fout)
{
    __shared__ u16 A_lds[32][136];   // [pt][ch]
    __shared__ u16 O_lds[32][136];   // [pt][g]
    const int t  = threadIdx.x;
    const int b  = blockIdx.x / NT32;
    const int n0 = (blockIdx.x % NT32) * 32;

    {
        const int chunk = t & 7;
        const int cbase = t >> 3;
        const float* base = feats + (size_t)b*CH*NPT + n0 + chunk*4;
        #pragma unroll
        for (int it = 0; it < 4; ++it) {
            int c = it*32 + cbase;
            float4 v = *(const float4*)(base + (size_t)c*NPT);
            A_lds[chunk*4+0][c] = f2bf1(v.x);
            A_lds[chunk*4+1][c] = f2bf1(v.y);
            A_lds[chunk*4+2][c] = f2bf1(v.z);
            A_lds[chunk*4+3][c] = f2bf1(v.w);
        }
    }

    const int lane = t & 63, wid = t >> 6;
    const int h = lane >> 4, r16 = lane & 15;
    const int gb = wid * 32;

    short8 bfrag[2][4];
    float sf[2], tf[2];
    #pragma unroll
    for (int T = 0; T < 2; ++T) {
        int g = gb + T*16 + r16;
        #pragma unroll
        for (int s = 0; s < 4; ++s)
            bfrag[T][s] = packrow(Wf + g*CH + s*32 + h*8);
        float inv = gf[g] * rsqrtf(vf[g] + EPSV);
        sf[T] = inv;
        tf[T] = bfv[g]*inv + betaf[g] - mf[g]*inv;
    }
    lds_barrier();

    #pragma unroll
    for (int sub = 0; sub < 2; ++sub) {
        short8 a[4];
        #pragma unroll
        for (int s = 0; s < 4; ++s)
            a[s] = *(const short8*)&A_lds[sub*16 + r16][s*32 + h*8];
        #pragma unroll
        for (int T = 0; T < 2; ++T) {
            f32x4 acc = {0.f, 0.f, 0.f, 0.f};
            #pragma unroll
            for (int s = 0; s < 4; ++s)
                acc = __builtin_amdgcn_mfma_f32_16x16x32_bf16(a[s], bfrag[T][s], acc, 0, 0, 0);
            #pragma unroll
            for (int r = 0; r < 4; ++r) {
                float y = fmaxf(fmaf(sf[T], acc[r], tf[T]), 0.f);
                O_lds[sub*16 + 4*h + r][gb + T*16 + r16] = f2bf1(y);
            }
        }
    }
    lds_barrier();

    {
        const int pp = t >> 3, cc = (t & 7) * 16;
        uint4 v0 = *(const uint4*)&O_lds[pp][cc];
        uint4 v1 = *(const uint4*)&O_lds[pp][cc + 8];
        u16* dst = Fout + ((size_t)b*NPT + n0 + pp)*CH + cc;
        *(uint4*)dst = v0;
        *(uint4*)(dst + 8) = v1;
    }
}

// ---------------- Kernel 2: block-shared A-plane, lgkm-only barriers -------
struct Pref { float4 m; uint4 f; };

__global__ __launch_bounds__(256) void k_main(
    const float* __restrict__ pts, const int* __restrict__ knn,
    const u16* __restrict__ F,
    const float* __restrict__ Wd, const float* __restrict__ bd,
    const float* __restrict__ gd, const float* __restrict__ betad,
    const float* __restrict__ md, const float* __restrict__ vd,
    const float* __restrict__ Wp, const float* __restrict__ bp,
    const float* __restrict__ gp, const float* __restrict__ betap,
    const float* __restrict__ mp, const float* __restrict__ vp,
    float* __restrict__ out)
{
    __shared__ u16   Abuf[2][16*128];      // 8 KB, XOR-swizzled rows
    __shared__ float4 meta[16][KNN];       // [dx,dy,dz,bitcast(idx)] 4.35 KB

    const int t  = threadIdx.x;
    const int b  = blockIdx.x / NT16;
    const int n0 = (blockIdx.x % NT16) * 16;

    const float* px = pts + (size_t)b*3*NPT;
    const float* py = px + NPT;
    const float* pz = py + NPT;

    // meta: neighbor idx + center-folded deltas (once per block)
    {
        const int* krow = knn + ((size_t)b*NPT + n0)*KNN;
        #pragma unroll 1
        for (int tau = t; tau < 16*KNN; tau += 256) {
            int r  = tau / KNN;
            int nb = krow[tau];
            float4 m;
            m.x = px[nb] - px[n0+r];
            m.y = py[nb] - py[n0+r];
            m.z = pz[nb] - pz[n0+r];
            m.w = __int_as_float(nb);
            (&meta[0][0])[tau] = m;
        }
    }
    lds_barrier();                         // meta ready

    const int p_t = t >> 4, j_t = t & 15, c0 = j_t*8;   // staging role
    const int lane = t & 63, wid = t >> 6;
    const int h = lane >> 4, r16 = lane & 15;
    const int gb = wid * 32;
    const u16* Fbj = F + (size_t)b*NPT*CH + c0;

    // hoisted LDS offsets
    const int wOff = p_t*128 + (c0 ^ ((p_t&7)*8));        // stage write (u16 idx)
    int rOff[4];
    #pragma unroll
    for (int s = 0; s < 4; ++s)
        rOff[s] = r16*128 + ((s*32 + h*8) ^ ((r16&7)*8)); // mfma reads

    auto issueK = [&](int k)->Pref {
        Pref P;
        P.m = meta[p_t][k];
        int nb = __float_as_int(P.m.w);
        P.f = *(const uint4*)(Fbj + (size_t)nb*CH);
        return P;
    };

    // prefetch planes 0,1 right away (latency hides under prologue below)
    Pref PA = issueK(0);
    Pref PB = issueK(1);

    // B fragments: s-scale folded into bf16 weights; epilogue uses max(acc,-t)
    short8 bfrag[2][4];
    float tpv[2];
    #pragma unroll
    for (int T = 0; T < 2; ++T) {
        int g = gb + T*16 + r16;
        float inv = gp[g] * rsqrtf(vp[g] + EPSV);
        #pragma unroll
        for (int s = 0; s < 4; ++s)
            bfrag[T][s] = packrow_scaled(Wp + g*CH + s*32 + h*8, inv);
        tpv[T] = bp[g]*inv + betap[g] - mp[g]*inv;
    }

    // d-branch coefficients for channels c0..c0+7, straight from global (L2-hot)
    f32x2 wx2[4], wy2[4], wz2[4], t2[4];
    #pragma unroll
    for (int q = 0; q < 4; ++q) {
        const int ca = c0 + 2*q, cb = ca + 1;
        float inva = gd[ca] * rsqrtf(vd[ca] + EPSV);
        float invb = gd[cb] * rsqrtf(vd[cb] + EPSV);
        wx2[q][0] = Wd[ca*3+0]*inva; wx2[q][1] = Wd[cb*3+0]*invb;
        wy2[q][0] = Wd[ca*3+1]*inva; wy2[q][1] = Wd[cb*3+1]*invb;
        wz2[q][0] = Wd[ca*3+2]*inva; wz2[q][1] = Wd[cb*3+2]*invb;
        t2[q][0]  = bd[ca]*inva + betad[ca] - md[ca]*inva;
        t2[q][1]  = bd[cb]*invb + betad[cb] - md[cb]*invb;
    }

    auto stage = [&](u16* A, const Pref& P) {
        const unsigned fw[4] = {P.f.x, P.f.y, P.f.z, P.f.w};
        const f32x2 z2 = {0.f, 0.f};
        unsigned pk[4];
        #pragma unroll
        for (int q = 0; q < 4; ++q) {
            f32x2 d = wx2[q]*P.m.x + wy2[q]*P.m.y + wz2[q]*P.m.z + t2[q];
            d = __builtin_elementwise_max(d, z2);
            f32x2 pr = d * bfpair(fw[q]);
            pk[q] = cvtpk(pr[0], pr[1]);
        }
        uint4 v; v.x = pk[0]; v.y = pk[1]; v.z = pk[2]; v.w = pk[3];
        *(uint4*)(A + wOff) = v;
    };

    f32x4 facc[2] = {};
    auto mfmaP = [&](const u16* A) {
        short8 a[4];
        #pragma unroll
        for (int s = 0; s < 4; ++s)
            a[s] = *(const short8*)(A + rOff[s]);
        #pragma unroll
        for (int T = 0; T < 2; ++T) {
            f32x4 acc = {0.f,0.f,0.f,0.f};
            #pragma unroll
            for (int s = 0; s < 4; ++s)
                acc = __builtin_amdgcn_mfma_f32_16x16x32_bf16(a[s], bfrag[T][s], acc, 0, 0, 0);
            f32x4 nt = {-tpv[T], -tpv[T], -tpv[T], -tpv[T]};
            facc[T] += __builtin_elementwise_max(acc, nt);   // relu folded: +17t at end
        }
    };

    // prologue: stage plane 0 into buf0; refill pipeline
    stage(Abuf[0], PA);
    PA = PB;
    PB = issueK(2);
    lds_barrier();

    int p = 0;
    #pragma unroll 1
    for (int k = 0; k < 16; ++k) {
        stage(Abuf[p^1], PA);              // plane k+1
        PA = PB;
        if (k + 3 <= 16) PB = issueK(k+3);
        mfmaP(Abuf[p]);                    // plane k
        lds_barrier();
        p ^= 1;
    }
    mfmaP(Abuf[p]);                        // plane 16

    #pragma unroll
    for (int T = 0; T < 2; ++T) {
        int g = gb + T*16 + r16;
        f32x4 o = facc[T] + (float)KNN * tpv[T];
        *(f32x4*)(out + ((size_t)b*CH + g)*NPT + n0 + 4*h) = o;
    }
}

extern "C" void kernel_launch(void* const* d_in, const int* in_sizes, int n_in,
                              void* d_out, int out_size, void* d_ws, size_t ws_size,
                              hipStream_t stream)
{
    const float* feats = (const float*)d_in[0];
    const float* pts   = (const float*)d_in[1];
    const int*   knn   = (const int*)d_in[2];
    const float* Wd    = (const float*)d_in[3];
    const float* bd    = (const float*)d_in[4];
    const float* gd    = (const float*)d_in[5];
    const float* betad = (const float*)d_in[6];
    const float* md    = (const float*)d_in[7];
    const float* vd    = (const float*)d_in[8];
    const float* Wf    = (const float*)d_in[9];
    const float* bfv   = (const float*)d_in[10];
    const float* gf    = (const float*)d_in[11];
    const float* betaf = (const float*)d_in[12];
    const float* mf    = (const float*)d_in[13];
    const float* vf    = (const float*)d_in[14];
    const float* Wp    = (const float*)d_in[15];
    const float* bp    = (const float*)d_in[16];
    const float* gp    = (const float*)d_in[17];
    const float* betap = (const float*)d_in[18];
    const float* mp    = (const float*)d_in[19];
    const float* vp    = (const float*)d_in[20];
    float* out = (float*)d_out;
    u16* Fws = (u16*)d_ws;   // B*N*128 bf16 = 10.24 MB

    k_feats<<<dim3(NB * NT32), 256, 0, stream>>>(feats, Wf, bfv, gf, betaf, mf, vf, Fws);
    k_main <<<dim3(NB * NT16), 256, 0, stream>>>(pts, knn, Fws, Wd, bd, gd, betad, md, vd,
                                                 Wp, bp, gp, betap, mp, vp, out);
}

// Round 8
// 75.540 us; speedup vs baseline: 4.7039x; 1.1121x over previous
//
#include <hip/hip_runtime.h>
#include <hip/hip_bf16.h>
#include <cstdint>
#include <cstddef>

#define NB 2
#define NPT 20000
#define KNN 17
#define CH 128
#define NT32 (NPT/32)
#define NPB 32                 // points per k_main block
#define NTILE 2                // 16-pt MFMA tiles per block
#define NPLANES (NTILE*KNN)    // 34
#define EPSV 1e-5f

typedef short short8 __attribute__((ext_vector_type(8)));
typedef float f32x4 __attribute__((ext_vector_type(4)));
typedef float f32x2 __attribute__((ext_vector_type(2)));
typedef unsigned short u16;

__device__ __forceinline__ unsigned cvtpk(float lo, float hi) {
    unsigned r;
    asm("v_cvt_pk_bf16_f32 %0, %1, %2" : "=v"(r) : "v"(lo), "v"(hi));
    return r;
}
__device__ __forceinline__ u16 f2bf1(float x) { return (u16)cvtpk(x, x); }
__device__ __forceinline__ f32x2 pk_fma(f32x2 a, f32x2 b, f32x2 c) {
    f32x2 d;
    asm("v_pk_fma_f32 %0, %1, %2, %3" : "=v"(d) : "v"(a), "v"(b), "v"(c));
    return d;
}
__device__ __forceinline__ f32x2 pk_mul(f32x2 a, f32x2 b) {
    f32x2 d;
    asm("v_pk_mul_f32 %0, %1, %2" : "=v"(d) : "v"(a), "v"(b));
    return d;
}
__device__ __forceinline__ f32x2 bfpair(unsigned w) {
    union { unsigned u; float f; } lo, hi;
    lo.u = w << 16; hi.u = w & 0xffff0000u;
    f32x2 r; r[0] = lo.f; r[1] = hi.f; return r;
}
__device__ __forceinline__ short8 packrow_scaled(const float* wrow, float s) {
    float4 w0 = *(const float4*)(wrow);
    float4 w1 = *(const float4*)(wrow + 4);
    uint4 uu;
    uu.x = cvtpk(w0.x*s, w0.y*s); uu.y = cvtpk(w0.z*s, w0.w*s);
    uu.z = cvtpk(w1.x*s, w1.y*s); uu.w = cvtpk(w1.z*s, w1.w*s);
    union { uint4 u; short8 s8; } cv; cv.u = uu; return cv.s8;
}
__device__ __forceinline__ short8 packrow(const float* wrow) {
    return packrow_scaled(wrow, 1.0f);
}
// barrier draining LDS ops only; global prefetches stay in flight
__device__ __forceinline__ void lds_barrier() {
    asm volatile("s_waitcnt lgkmcnt(0)\n\ts_barrier" ::: "memory");
}

// ---------------- Kernel 1: F[b][n][g] = relu(bn(Wf @ feats[:,n])), bf16 ----
__global__ __launch_bounds__(256) void k_feats(
    const float* __restrict__ feats, const float* __restrict__ Wf,
    const float* __restrict__ bfv, const float* __restrict__ gf,
    const float* __restrict__ betaf, const float* __restrict__ mf,
    const float* __restrict__ vf, u16* __restrict__ Fout)
{
    __shared__ u16 A_lds[32][136];
    __shared__ u16 O_lds[32][136];
    const int t  = threadIdx.x;
    const int b  = blockIdx.x / NT32;
    const int n0 = (blockIdx.x % NT32) * 32;

    {
        const int chunk = t & 7;
        const int cbase = t >> 3;
        const float* base = feats + (size_t)b*CH*NPT + n0 + chunk*4;
        #pragma unroll
        for (int it = 0; it < 4; ++it) {
            int c = it*32 + cbase;
            float4 v = *(const float4*)(base + (size_t)c*NPT);
            A_lds[chunk*4+0][c] = f2bf1(v.x);
            A_lds[chunk*4+1][c] = f2bf1(v.y);
            A_lds[chunk*4+2][c] = f2bf1(v.z);
            A_lds[chunk*4+3][c] = f2bf1(v.w);
        }
    }

    const int lane = t & 63, wid = t >> 6;
    const int h = lane >> 4, r16 = lane & 15;
    const int gb = wid * 32;

    short8 bfrag[2][4];
    float sf[2], tf[2];
    #pragma unroll
    for (int T = 0; T < 2; ++T) {
        int g = gb + T*16 + r16;
        #pragma unroll
        for (int s = 0; s < 4; ++s)
            bfrag[T][s] = packrow(Wf + g*CH + s*32 + h*8);
        float inv = gf[g] * rsqrtf(vf[g] + EPSV);
        sf[T] = inv;
        tf[T] = bfv[g]*inv + betaf[g] - mf[g]*inv;
    }
    lds_barrier();

    #pragma unroll
    for (int sub = 0; sub < 2; ++sub) {
        short8 a[4];
        #pragma unroll
        for (int s = 0; s < 4; ++s)
            a[s] = *(const short8*)&A_lds[sub*16 + r16][s*32 + h*8];
        #pragma unroll
        for (int T = 0; T < 2; ++T) {
            f32x4 acc = {0.f, 0.f, 0.f, 0.f};
            #pragma unroll
            for (int s = 0; s < 4; ++s)
                acc = __builtin_amdgcn_mfma_f32_16x16x32_bf16(a[s], bfrag[T][s], acc, 0, 0, 0);
            #pragma unroll
            for (int r = 0; r < 4; ++r) {
                float y = fmaxf(fmaf(sf[T], acc[r], tf[T]), 0.f);
                O_lds[sub*16 + 4*h + r][gb + T*16 + r16] = f2bf1(y);
            }
        }
    }
    lds_barrier();

    {
        const int pp = t >> 3, cc = (t & 7) * 16;
        uint4 v0 = *(const uint4*)&O_lds[pp][cc];
        uint4 v1 = *(const uint4*)&O_lds[pp][cc + 8];
        u16* dst = Fout + ((size_t)b*NPT + n0 + pp)*CH + cc;
        *(uint4*)dst = v0;
        *(uint4*)(dst + 8) = v1;
    }
}

// ---------------- Kernel 2: 32-pt blocks, flat 34-plane quad-chunk pipeline
struct Pref { float4 m; uint4 f; };

__global__ __launch_bounds__(256) void k_main(
    const float* __restrict__ pts, const int* __restrict__ knn,
    const u16* __restrict__ F,
    const float* __restrict__ Wd, const float* __restrict__ bd,
    const float* __restrict__ gd, const float* __restrict__ betad,
    const float* __restrict__ md, const float* __restrict__ vd,
    const float* __restrict__ Wp, const float* __restrict__ bp,
    const float* __restrict__ gp, const float* __restrict__ betap,
    const float* __restrict__ mp, const float* __restrict__ vp,
    float* __restrict__ out)
{
    __shared__ u16   Abuf[2][4][16*128];        // 32 KB: [half][slot]
    __shared__ float4 metaL[NPLANES][16];       // 8.7 KB: plane-major meta

    const int t  = threadIdx.x;
    const int b  = blockIdx.x / NT32;
    const int n0 = (blockIdx.x % NT32) * NPB;

    const float* px = pts + (size_t)b*3*NPT;
    const float* py = px + NPT;
    const float* pz = py + NPT;

    // fill metaL[pi][p] = {dx,dy,dz, byte-offset of F row}, pi = tile*17+k
    {
        const int* kbase = knn + ((size_t)b*NPT + n0)*KNN;
        #pragma unroll 1
        for (int e = t; e < NPLANES*16; e += 256) {
            int pi = e >> 4, p = e & 15;
            int tile = (pi >= KNN) ? 1 : 0;
            int k  = pi - tile*KNN;
            int row = tile*16 + p;
            int nb = kbase[row*KNN + k];
            float4 m;
            m.x = px[nb] - px[n0+row];
            m.y = py[nb] - py[n0+row];
            m.z = pz[nb] - pz[n0+row];
            m.w = __int_as_float(nb << 8);             // byte offset (256 B/row)
            metaL[pi][p] = m;
        }
    }
    lds_barrier();

    const int p_t = t >> 4, j_t = t & 15, c0 = j_t*8;
    const int lane = t & 63, wid = t >> 6;
    const int h = lane >> 4, r16 = lane & 15;
    const int gb = wid * 32;
    const char* FbjB = (const char*)(F + (size_t)b*NPT*CH + c0);

    const int wOff = p_t*128 + (c0 ^ ((p_t&7)*8));
    int rOff[4];
    #pragma unroll
    for (int s = 0; s < 4; ++s)
        rOff[s] = r16*128 + ((s*32 + h*8) ^ ((r16&7)*8));

    auto issueK = [&](int pi)->Pref {
        Pref P;
        P.m = metaL[pi][p_t];
        P.f = *(const uint4*)(FbjB + __float_as_int(P.m.w));
        return P;
    };

    Pref P[4];
    #pragma unroll
    for (int i = 0; i < 4; ++i) P[i] = issueK(i);      // quad 0 gathers in flight

    // B fragments (scale folded) + folded BN offsets — hides gather latency
    short8 bfrag[2][4];
    float tpv[2];
    #pragma unroll
    for (int T = 0; T < 2; ++T) {
        int g = gb + T*16 + r16;
        float inv = gp[g] * rsqrtf(vp[g] + EPSV);
        #pragma unroll
        for (int s = 0; s < 4; ++s)
            bfrag[T][s] = packrow_scaled(Wp + g*CH + s*32 + h*8, inv);
        tpv[T] = bp[g]*inv + betap[g] - mp[g]*inv;
    }

    f32x2 wx2[4], wy2[4], wz2[4], t2[4];
    #pragma unroll
    for (int q = 0; q < 4; ++q) {
        const int ca = c0 + 2*q, cb = ca + 1;
        float inva = gd[ca] * rsqrtf(vd[ca] + EPSV);
        float invb = gd[cb] * rsqrtf(vd[cb] + EPSV);
        wx2[q][0] = Wd[ca*3+0]*inva; wx2[q][1] = Wd[cb*3+0]*invb;
        wy2[q][0] = Wd[ca*3+1]*inva; wy2[q][1] = Wd[cb*3+1]*invb;
        wz2[q][0] = Wd[ca*3+2]*inva; wz2[q][1] = Wd[cb*3+2]*invb;
        t2[q][0]  = bd[ca]*inva + betad[ca] - md[ca]*inva;
        t2[q][1]  = bd[cb]*invb + betad[cb] - md[cb]*invb;
    }

    auto stage = [&](u16* plane, const Pref& Pr) {
        const unsigned fw[4] = {Pr.f.x, Pr.f.y, Pr.f.z, Pr.f.w};
        const f32x2 z2 = {0.f, 0.f};
        f32x2 dx2 = {Pr.m.x, Pr.m.x}, dy2 = {Pr.m.y, Pr.m.y}, dz2 = {Pr.m.z, Pr.m.z};
        unsigned pk[4];
        #pragma unroll
        for (int q = 0; q < 4; ++q) {
            f32x2 d = pk_fma(wx2[q], dx2, pk_fma(wy2[q], dy2, pk_fma(wz2[q], dz2, t2[q])));
            d = __builtin_elementwise_max(d, z2);
            f32x2 pr = pk_mul(d, bfpair(fw[q]));
            pk[q] = cvtpk(pr[0], pr[1]);
        }
        uint4 v; v.x = pk[0]; v.y = pk[1]; v.z = pk[2]; v.w = pk[3];
        *(uint4*)(plane + wOff) = v;
    };

    f32x4 facc[2] = {};
    auto mfmaP = [&](const u16* plane) {
        short8 a[4];
        #pragma unroll
        for (int s = 0; s < 4; ++s)
            a[s] = *(const short8*)(plane + rOff[s]);
        #pragma unroll
        for (int T = 0; T < 2; ++T) {
            f32x4 acc = {0.f,0.f,0.f,0.f};
            #pragma unroll
            for (int s = 0; s < 4; ++s)
                acc = __builtin_amdgcn_mfma_f32_16x16x32_bf16(a[s], bfrag[T][s], acc, 0, 0, 0);
            f32x4 nt = {-tpv[T], -tpv[T], -tpv[T], -tpv[T]};
            facc[T] += __builtin_elementwise_max(acc, nt);
        }
    };
    auto writeout = [&](int tile) {
        #pragma unroll
        for (int T = 0; T < 2; ++T) {
            int g = gb + T*16 + r16;
            f32x4 o = facc[T] + (float)KNN * tpv[T];
            *(f32x4*)(out + ((size_t)b*CH + g)*NPT + n0 + tile*16 + 4*h) = o;
            facc[T][0]=0.f; facc[T][1]=0.f; facc[T][2]=0.f; facc[T][3]=0.f;
        }
    };

    // prologue: stage quad0 -> half0, issue quad1
    #pragma unroll
    for (int i = 0; i < 4; ++i) stage(Abuf[0][i], P[i]);
    #pragma unroll
    for (int i = 0; i < 4; ++i) P[i] = issueK(4+i);
    lds_barrier();

    // main: chunks c=0..5 — mfma quad c, stage quad c+1, issue quad c+2
    #pragma unroll 1
    for (int c = 0; c < 6; ++c) {
        const int H = c & 1;
        u16* sb = &Abuf[H^1][0][0];
        #pragma unroll
        for (int i = 0; i < 4; ++i) stage(sb + i*2048, P[i]);
        #pragma unroll
        for (int i = 0; i < 4; ++i) P[i] = issueK(4*c + 8 + i);   // ≤ 31
        const u16* mb = &Abuf[H][0][0];
        #pragma unroll
        for (int i = 0; i < 4; ++i) {
            mfmaP(mb + i*2048);
            if (i == 0 && c == 4) writeout(0);     // after plane 16
        }
        lds_barrier();
    }
    // c=6: stage quad7 -> half1, issue planes 32,33, mfma quad6 (half0)
    {
        #pragma unroll
        for (int i = 0; i < 4; ++i) stage(&Abuf[1][i][0], P[i]);
        P[0] = issueK(32);
        P[1] = issueK(33);
        #pragma unroll
        for (int i = 0; i < 4; ++i) mfmaP(&Abuf[0][i][0]);
        lds_barrier();
    }
    // c=7: stage planes 32,33 -> half0 slots 0,1, mfma quad7 (half1)
    {
        stage(&Abuf[0][0][0], P[0]);
        stage(&Abuf[0][1][0], P[1]);
        #pragma unroll
        for (int i = 0; i < 4; ++i) mfmaP(&Abuf[1][i][0]);
        lds_barrier();
    }
    // tail: planes 32,33
    mfmaP(&Abuf[0][0][0]);
    mfmaP(&Abuf[0][1][0]);
    writeout(1);
}

extern "C" void kernel_launch(void* const* d_in, const int* in_sizes, int n_in,
                              void* d_out, int out_size, void* d_ws, size_t ws_size,
                              hipStream_t stream)
{
    const float* feats = (const float*)d_in[0];
    const float* pts   = (const float*)d_in[1];
    const int*   knn   = (const int*)d_in[2];
    const float* Wd    = (const float*)d_in[3];
    const float* bd    = (const float*)d_in[4];
    const float* gd    = (const float*)d_in[5];
    const float* betad = (const float*)d_in[6];
    const float* md    = (const float*)d_in[7];
    const float* vd    = (const float*)d_in[8];
    const float* Wf    = (const float*)d_in[9];
    const float* bfv   = (const float*)d_in[10];
    const float* gf    = (const float*)d_in[11];
    const float* betaf = (const float*)d_in[12];
    const float* mf    = (const float*)d_in[13];
    const float* vf    = (const float*)d_in[14];
    const float* Wp    = (const float*)d_in[15];
    const float* bp    = (const float*)d_in[16];
    const float* gp    = (const float*)d_in[17];
    const float* betap = (const float*)d_in[18];
    const float* mp    = (const float*)d_in[19];
    const float* vp    = (const float*)d_in[20];
    float* out = (float*)d_out;
    u16* Fws = (u16*)d_ws;   // B*N*128 bf16 = 10.24 MB

    k_feats<<<dim3(NB * NT32), 256, 0, stream>>>(feats, Wf, bfv, gf, betaf, mf, vf, Fws);
    k_main <<<dim3(NB * NT32), 256, 0, stream>>>(pts, knn, Fws, Wd, bd, gd, betad, md, vd,
                                                 Wp, bp, gp, betap, mp, vp, out);
}